// Round 4
// baseline (5788.842 us; speedup 1.0000x reference)
//
#include <hip/hip_runtime.h>

#define BB 128
#define TT 1024
#define INP 54
#define HUM 64
#define NPSI 96540
#define OFF_BH 65536
#define OFF_WIH 65792
#define OFF_C 79616
#define OFF_D 96000
#define OUT_MU 8388608
#define OUT_LS 8390656
#define OUT_HL 8392704

typedef unsigned int u32;
typedef unsigned short u16;
typedef _Float16 h2 __attribute__((ext_vector_type(2)));

__device__ __forceinline__ u32 pk(float a, float b) {
    h2 v; v.x = (_Float16)a; v.y = (_Float16)b;
    return __builtin_bit_cast(u32, v);
}
__device__ __forceinline__ float f16tof(u16 v) {
    return (float)__builtin_bit_cast(_Float16, v);
}
__device__ __forceinline__ u16 ftof16(float v) {
    return __builtin_bit_cast(u16, (_Float16)v);
}
__device__ __forceinline__ h2 bch2(u32 a) { return __builtin_bit_cast(h2, a); }
// packed f16 fma: 2 MACs per inst (v_pk_fma_f16 with -ffp-contract=fast)
__device__ __forceinline__ h2 pfma(u32 a, u32 b, h2 c) {
    return bch2(a) * bch2(b) + c;
}
__device__ __forceinline__ float h2red4(h2 a, h2 b, h2 c, h2 d) {
    h2 s = (a + b) + (c + d);
    return (float)s.x + (float)s.y;
}
__device__ __forceinline__ float fsig(float x) { return 1.f / (1.f + __expf(-x)); }
__device__ __forceinline__ float ftanh(float x) { float e = __expf(2.f * x); return 1.f - 2.f / (e + 1.f); }

// quad reduction on the VALU pipe (DPP): all 4 lanes end with the full sum
__device__ __forceinline__ float qred(float v) {
#if __has_builtin(__builtin_amdgcn_mov_dpp)
    int x = __builtin_bit_cast(int, v);
    v += __builtin_bit_cast(float, __builtin_amdgcn_mov_dpp(x, 0xB1, 0xF, 0xF, true)); // quad_perm [1,0,3,2]
    x = __builtin_bit_cast(int, v);
    v += __builtin_bit_cast(float, __builtin_amdgcn_mov_dpp(x, 0x4E, 0xF, 0xF, true)); // quad_perm [2,3,0,1]
    return v;
#else
    v += __shfl_xor(v, 1); v += __shfl_xor(v, 2);
    return v;
#endif
}

// ------------------------------------------------------- x-side projections --
__global__ __launch_bounds__(768) void gemm_x_kernel(
    const float* __restrict__ inp, const float* __restrict__ W0,
    const u16* __restrict__ psi16, int mode, int t0, int len, int ct, int nt,
    u16* __restrict__ gout)
{
    const int tid = threadIdx.x;
    const int b = blockIdx.x / nt, tc = blockIdx.x % nt;
    const int gr = tid;
    float w[INP];
    if (mode == 0 || gr < 512) {
        const float* wsrc = W0 + (size_t)gr * INP;
#pragma unroll
        for (int c = 0; c < INP; ++c) w[c] = wsrc[c];
    } else {
        const u16* wsrc = psi16 + (size_t)b * NPSI + OFF_WIH + (size_t)(gr - 512) * INP;
#pragma unroll
        for (int c = 0; c < INP; ++c) w[c] = f16tof(wsrc[c]);
    }
    const int tb = tc * 128;
    const int te = (tb + 128 < len) ? tb + 128 : len;
    for (int tl = tb; tl < te; ++tl) {
        const float* xr = inp + ((size_t)b * TT + t0 + tl) * INP;
        float a = 0.f;
#pragma unroll
        for (int c = 0; c < INP; ++c) a = __builtin_fmaf(xr[c], w[c], a);
        gout[((size_t)b * ct + tl) * 768 + gr] = ftof16(a);
    }
}

// ---------------------------------------------------------------- encoder ---
__global__ __launch_bounds__(1024) void enc_scan_kernel(
    const u16* __restrict__ gi, int t0, int len, int ct,
    const float* __restrict__ Whh, const float* __restrict__ bih,
    const float* __restrict__ bhh, float* __restrict__ hcarry)
{
    __shared__ __align__(16) u32 hpp[2][144];
    const int tid = threadIdx.x, b = blockIdx.x;
    const int l = tid & 3, j = tid >> 2;

    u32 wr[32], wz[32], wn[32];
    {
        const float* pr = Whh + (size_t)j * 256 + 64 * l;
        const float* pz = Whh + (size_t)(256 + j) * 256 + 64 * l;
        const float* pn = Whh + (size_t)(512 + j) * 256 + 64 * l;
#pragma unroll
        for (int c = 0; c < 32; ++c) {
            wr[c] = pk(pr[2 * c], pr[2 * c + 1]);
            wz[c] = pk(pz[2 * c], pz[2 * c + 1]);
            wn[c] = pk(pn[2 * c], pn[2 * c + 1]);
        }
    }
    const float brb = bih[j] + bhh[j];
    const float bzb = bih[256 + j] + bhh[256 + j];
    const float bib = bih[512 + j];
    const float bhb = bhh[512 + j];
    float hcur = 0.f;
    if (t0 > 0) hcur = hcarry[(size_t)b * 256 + j];
    if (tid < 128) {
        u32 hv = 0u;
        if (t0 > 0) hv = pk(hcarry[(size_t)b * 256 + 2 * tid], hcarry[(size_t)b * 256 + 2 * tid + 1]);
        hpp[0][36 * (tid >> 5) + (tid & 31)] = hv;
    }
    __syncthreads();

    const u16* gbase = gi + (size_t)b * ct * 768;
    float c0 = f16tof(gbase[j]);
    float c1 = f16tof(gbase[256 + j]);
    float c2 = f16tof(gbase[512 + j]);
    const h2 z2 = {(_Float16)0.f, (_Float16)0.f};
    for (int tl = 0; tl < len; ++tl) {
        const int p = tl & 1;
        float n0 = 0, n1 = 0, n2 = 0;
        if (tl + 1 < len) {
            const u16* gn = gbase + (size_t)(tl + 1) * 768;
            n0 = f16tof(gn[j]); n1 = f16tof(gn[256 + j]); n2 = f16tof(gn[512 + j]);
        }
        h2 vr[4], vz[4], vn[4];
#pragma unroll
        for (int i = 0; i < 4; ++i) { vr[i] = z2; vz[i] = z2; vn[i] = z2; }
        const uint4* hq = (const uint4*)hpp[p];
#pragma unroll
        for (int cc = 0; cc < 8; ++cc) {
            uint4 q = hq[9 * l + cc];
            const int ai = cc >> 1;
            vr[ai] = pfma(wr[4 * cc + 0], q.x, vr[ai]);
            vz[ai] = pfma(wz[4 * cc + 0], q.x, vz[ai]);
            vn[ai] = pfma(wn[4 * cc + 0], q.x, vn[ai]);
            vr[ai] = pfma(wr[4 * cc + 1], q.y, vr[ai]);
            vz[ai] = pfma(wz[4 * cc + 1], q.y, vz[ai]);
            vn[ai] = pfma(wn[4 * cc + 1], q.y, vn[ai]);
            vr[ai] = pfma(wr[4 * cc + 2], q.z, vr[ai]);
            vz[ai] = pfma(wz[4 * cc + 2], q.z, vz[ai]);
            vn[ai] = pfma(wn[4 * cc + 2], q.z, vn[ai]);
            vr[ai] = pfma(wr[4 * cc + 3], q.w, vr[ai]);
            vz[ai] = pfma(wz[4 * cc + 3], q.w, vz[ai]);
            vn[ai] = pfma(wn[4 * cc + 3], q.w, vn[ai]);
        }
        float ar = qred(h2red4(vr[0], vr[1], vr[2], vr[3]));
        float az = qred(h2red4(vz[0], vz[1], vz[2], vz[3]));
        float ah = qred(h2red4(vn[0], vn[1], vn[2], vn[3]));
        // all quad lanes hold the sums -> compute gates redundantly (no branch)
        {
            float r = fsig(ar + c0 + brb);
            float z = fsig(az + c1 + bzb);
            float nn = ftanh(c2 + bib + r * (ah + bhb));
            float hn = (1.f - z) * nn + z * hcur;
            hcur = hn;
            float ho = __shfl_xor(hn, 4);
            if ((tid & 7) == 0) {
                int g = j >> 1;
                hpp[p ^ 1][36 * (g >> 5) + (g & 31)] = pk(hn, ho);
            }
        }
        c0 = n0; c1 = n1; c2 = n2;
        __syncthreads();
    }
    if (l == 0) hcarry[(size_t)b * 256 + j] = hcur;
}

// ----------------------------------------------------------------- latent ---
__global__ __launch_bounds__(256) void latent_kernel(
    const float* __restrict__ henc, const float* __restrict__ eps,
    const float* __restrict__ to_mu, const float* __restrict__ to_ls,
    const float* __restrict__ W1, const float* __restrict__ b1,
    const float* __restrict__ W2, const float* __restrict__ b2,
    float* __restrict__ psi2, float* __restrict__ out)
{
    __shared__ float h[256], zz[16], p1[256];
    const int tid = threadIdx.x, b = blockIdx.x;
    h[tid] = henc[(size_t)b * 256 + tid];
    __syncthreads();
    if (tid < 16) {
        float m = 0, s = 0;
        for (int k = 0; k < 256; ++k) {
            m += h[k] * to_mu[tid * 256 + k];
            s += h[k] * to_ls[tid * 256 + k];
        }
        out[OUT_MU + b * 16 + tid] = m;
        out[OUT_LS + b * 16 + tid] = s;
        zz[tid] = m + eps[b * 16 + tid] * __expf(s);
    }
    __syncthreads();
    {
        float a = b1[tid];
        for (int k = 0; k < 16; ++k) a += zz[k] * W1[tid * 16 + k];
        p1[tid] = ftanh(a);
    }
    __syncthreads();
    if (tid < 32) {
        float a = b2[tid];
        for (int k = 0; k < 256; ++k) a += p1[k] * W2[tid * 256 + k];
        psi2[b * 32 + tid] = a;
    }
}

// ------------------------------------------------------------------- psi3 ---
__global__ __launch_bounds__(256) void psi3_kernel(
    const float* __restrict__ psi2, const float* __restrict__ W3,
    const float* __restrict__ b3, u16* __restrict__ psi16)
{
    __shared__ float sp2[128 * 32];
    __shared__ float w3t[256 * 33];
    const int tid = threadIdx.x;
    const int n0 = blockIdx.x * 256;
    for (int idx = tid; idx < 4096; idx += 256) sp2[idx] = psi2[idx];
    for (int idx = tid; idx < 8192; idx += 256) {
        int row = idx >> 5, k = idx & 31;
        int n = n0 + row;
        w3t[row * 33 + k] = (n < NPSI) ? W3[(size_t)n * 32 + k] : 0.f;
    }
    __syncthreads();
    const int n = n0 + tid;
    if (n < NPSI) {
        float w[32];
#pragma unroll
        for (int k = 0; k < 32; ++k) w[k] = w3t[tid * 33 + k];
        const float bv = b3[n];
        for (int bi = 0; bi < 128; ++bi) {
            float a = bv;
#pragma unroll
            for (int k = 0; k < 32; ++k) a += sp2[bi * 32 + k] * w[k];
            psi16[(size_t)bi * NPSI + n] = ftof16(a);
        }
    }
}

// ------------------------------- decoder scan + pipelined fused C_p einsum --
__global__ __launch_bounds__(1024) void dec_scan_kernel(
    const u16* __restrict__ gx, int t0, int len, int ct,
    const float* __restrict__ state, const float* __restrict__ gWhh,
    const float* __restrict__ gbias, const u16* __restrict__ psi16,
    float* __restrict__ dcarry, float* __restrict__ out)
{
    __shared__ __align__(16) u32 hpp[2][144];
    __shared__ u32 cp[64 * 129];      // [o][pair q], stride 129 -> 2-way (free)
    __shared__ float part[2][16 * 64];
    const int tid = threadIdx.x, b = blockIdx.x;
    const int l = tid & 3, j = tid >> 2;
    const u16* pc = psi16 + (size_t)b * NPSI;

    u32 wz[32], wr[32], wp[32];
#pragma unroll
    for (int c = 0; c < 32; ++c) {
        const int h0 = 64 * l + 2 * c;
        wz[c] = pk(gWhh[(size_t)h0 * 512 + j], gWhh[(size_t)(h0 + 1) * 512 + j]);
        wr[c] = pk(gWhh[(size_t)h0 * 512 + 256 + j], gWhh[(size_t)(h0 + 1) * 512 + 256 + j]);
        wp[c] = (u32)pc[(size_t)h0 * 256 + j] | ((u32)pc[(size_t)(h0 + 1) * 256 + j] << 16);
    }
    const float gzb = gbias[j], grb = gbias[256 + j];
    const float bhb = f16tof(pc[OFF_BH + j]);
    for (int idx = tid; idx < 8192; idx += 1024) {
        const int q = idx >> 6, o = idx & 63;
        cp[o * 129 + q] = (u32)pc[OFF_C + (size_t)(2 * q) * 64 + o]
                        | ((u32)pc[OFF_C + (size_t)(2 * q + 1) * 64 + o] << 16);
    }
    const float* hsrc = (t0 == 0) ? state : dcarry;
    float hcur = hsrc[(size_t)b * 256 + j];
    if (tid < 128) hpp[0][36 * (tid >> 5) + (tid & 31)] =
        pk(hsrc[(size_t)b * 256 + 2 * tid], hsrc[(size_t)b * 256 + 2 * tid + 1]);
    __syncthreads();

    const u16* gbase = gx + (size_t)b * ct * 768;
    const int o = tid & 63, s = tid >> 6;
    const int hqi = 36 * (s >> 2) + ((8 * s) & 31);   // hpp idx of pair 8s
    float c0 = f16tof(gbase[j]);
    float c1 = f16tof(gbase[256 + j]);
    float c2 = f16tof(gbase[512 + j]);
    const h2 z2 = {(_Float16)0.f, (_Float16)0.f};

    for (int tl = 0; tl < len; ++tl) {
        const int p = tl & 1;
        float n0 = 0, n1 = 0, n2 = 0;
        if (tl + 1 < len) {
            const u16* gn = gbase + (size_t)(tl + 1) * 768;
            n0 = f16tof(gn[j]); n1 = f16tof(gn[256 + j]); n2 = f16tof(gn[512 + j]);
        }
        // yhat partials for y_{t0+tl-1} from hpp[p] (wave-uniform broadcast)
        {
            const uint4* h2q = (const uint4*)&hpp[p][hqi];
            uint4 qa = h2q[0], qb = h2q[1];
            const int cbase = o * 129 + s * 8;
            h2 p0 = z2, p1 = z2;
            p0 = pfma(qa.x, cp[cbase + 0], p0);
            p1 = pfma(qa.y, cp[cbase + 1], p1);
            p0 = pfma(qa.z, cp[cbase + 2], p0);
            p1 = pfma(qa.w, cp[cbase + 3], p1);
            p0 = pfma(qb.x, cp[cbase + 4], p0);
            p1 = pfma(qb.y, cp[cbase + 5], p1);
            p0 = pfma(qb.z, cp[cbase + 6], p0);
            p1 = pfma(qb.w, cp[cbase + 7], p1);
            h2 ps = p0 + p1;
            part[p][s * 64 + o] = (float)ps.x + (float)ps.y;
        }
        // recurrent matvec (packed f16 fma, 4 accums/gate)
        h2 vz[4], vr[4], vp[4];
#pragma unroll
        for (int i = 0; i < 4; ++i) { vz[i] = z2; vr[i] = z2; vp[i] = z2; }
        const uint4* hq = (const uint4*)hpp[p];
#pragma unroll
        for (int cc = 0; cc < 8; ++cc) {
            uint4 q = hq[9 * l + cc];
            const int ai = cc >> 1;
            vz[ai] = pfma(wz[4 * cc + 0], q.x, vz[ai]);
            vr[ai] = pfma(wr[4 * cc + 0], q.x, vr[ai]);
            vp[ai] = pfma(wp[4 * cc + 0], q.x, vp[ai]);
            vz[ai] = pfma(wz[4 * cc + 1], q.y, vz[ai]);
            vr[ai] = pfma(wr[4 * cc + 1], q.y, vr[ai]);
            vp[ai] = pfma(wp[4 * cc + 1], q.y, vp[ai]);
            vz[ai] = pfma(wz[4 * cc + 2], q.z, vz[ai]);
            vr[ai] = pfma(wr[4 * cc + 2], q.z, vr[ai]);
            vp[ai] = pfma(wp[4 * cc + 2], q.z, vp[ai]);
            vz[ai] = pfma(wz[4 * cc + 3], q.w, vz[ai]);
            vr[ai] = pfma(wr[4 * cc + 3], q.w, vr[ai]);
            vp[ai] = pfma(wp[4 * cc + 3], q.w, vp[ai]);
        }
        float az = qred(h2red4(vz[0], vz[1], vz[2], vz[3]));
        float ar = qred(h2red4(vr[0], vr[1], vr[2], vr[3]));
        float ap = qred(h2red4(vp[0], vp[1], vp[2], vp[3]));
        {
            float zt = fsig(az + c0 + gzb);
            float rt = fsig(ar + c1 + grb);
            float eta = ftanh(c2 + rt * ftanh(ap + bhb));
            float hn = zt * hcur + (1.f - zt) * eta;
            hcur = hn;
            float ho = __shfl_xor(hn, 4);
            if ((tid & 7) == 0) {
                int g = j >> 1;
                hpp[p ^ 1][36 * (g >> 5) + (g & 31)] = pk(hn, ho);
            }
        }
        // reduce previous step's partials -> y_{t0+tl-2}
        if (tid < 64 && tl >= 1) {
            const int yi = t0 + tl - 2;
            if (yi >= 0) {
                float y = 0.f;
#pragma unroll
                for (int s2 = 0; s2 < 16; ++s2) y += part[p ^ 1][s2 * 64 + tid];
                out[((size_t)b * TT + yi) * HUM + tid] = y;
            }
        }
        c0 = n0; c1 = n1; c2 = n2;
        __syncthreads();
    }
    // tail: y_{t0+len-2} from part[(len-1)&1]; partials+reduce for y_{t0+len-1}
    {
        const int pf = (len - 1) & 1;
        if (tid < 64 && t0 + len - 2 >= 0) {
            float y = 0.f;
#pragma unroll
            for (int s2 = 0; s2 < 16; ++s2) y += part[pf][s2 * 64 + tid];
            out[((size_t)b * TT + t0 + len - 2) * HUM + tid] = y;
        }
        const int pl = len & 1;
        {
            const uint4* h2q = (const uint4*)&hpp[pl][hqi];
            uint4 qa = h2q[0], qb = h2q[1];
            const int cbase = o * 129 + s * 8;
            h2 p0 = z2, p1 = z2;
            p0 = pfma(qa.x, cp[cbase + 0], p0);
            p1 = pfma(qa.y, cp[cbase + 1], p1);
            p0 = pfma(qa.z, cp[cbase + 2], p0);
            p1 = pfma(qa.w, cp[cbase + 3], p1);
            p0 = pfma(qb.x, cp[cbase + 4], p0);
            p1 = pfma(qb.y, cp[cbase + 5], p1);
            p0 = pfma(qb.z, cp[cbase + 6], p0);
            p1 = pfma(qb.w, cp[cbase + 7], p1);
            h2 ps = p0 + p1;
            part[pl][s * 64 + o] = (float)ps.x + (float)ps.y;
        }
        __syncthreads();
        if (tid < 64) {
            float y = 0.f;
#pragma unroll
            for (int s2 = 0; s2 < 16; ++s2) y += part[pl][s2 * 64 + tid];
            out[((size_t)b * TT + t0 + len - 1) * HUM + tid] = y;
        }
    }
    if (l == 0) {
        dcarry[(size_t)b * 256 + j] = hcur;
        if (t0 + len == TT) out[OUT_HL + (size_t)b * 256 + j] = hcur;
    }
}

// ------------------------------------------------- x add + D_p einsum fixup --
__global__ __launch_bounds__(256) void post_kernel(
    const float* __restrict__ inp, const u16* __restrict__ psi16,
    float* __restrict__ out)
{
    __shared__ float xs[128][55];
    __shared__ float ds[INP][10];
    const int tid = threadIdx.x;
    const int b = blockIdx.x >> 3, tile = blockIdx.x & 7;
    const int t0 = tile * 128;
    const u16* pc = psi16 + (size_t)b * NPSI;
    for (int idx = tid; idx < 540; idx += 256)
        ds[idx / 10][idx % 10] = f16tof(pc[OFF_D + idx]);
    for (int idx = tid; idx < 128 * INP; idx += 256) {
        const int t = idx / INP, d = idx % INP;
        xs[t][d] = inp[((size_t)b * TT + t0 + t) * INP + d];
    }
    __syncthreads();
    for (int i = 0; i < 32; ++i) {
        const int flat = i * 256 + tid;
        const int t = flat >> 6, o = flat & 63;
        const size_t oi = ((size_t)b * TT + t0 + t) * HUM + o;
        float y = out[oi];
        if (o < INP) y += xs[t][o];
        else {
            float acc = 0.f;
            for (int d = 0; d < INP; ++d) acc += xs[t][d] * ds[d][o - INP];
            y += acc;
        }
        out[oi] = y;
    }
}

// ----------------------------------------------------------------- launch ---
extern "C" void kernel_launch(void* const* d_in, const int* in_sizes, int n_in,
                              void* d_out, int out_size, void* d_ws, size_t ws_size,
                              hipStream_t stream)
{
    const float* inputs = (const float*)d_in[0];
    const float* state  = (const float*)d_in[1];
    const float* eps    = (const float*)d_in[2];
    const float* eWih   = (const float*)d_in[3];
    const float* eWhh   = (const float*)d_in[4];
    const float* ebih   = (const float*)d_in[5];
    const float* ebhh   = (const float*)d_in[6];
    const float* to_mu  = (const float*)d_in[7];
    const float* to_ls  = (const float*)d_in[8];
    const float* W1     = (const float*)d_in[9];
    const float* b1     = (const float*)d_in[10];
    const float* W2     = (const float*)d_in[11];
    const float* b2     = (const float*)d_in[12];
    const float* W3     = (const float*)d_in[13];
    const float* b3     = (const float*)d_in[14];
    const float* gWih   = (const float*)d_in[15];
    const float* gWhh   = (const float*)d_in[16];
    const float* gbias  = (const float*)d_in[17];
    float* out = (float*)d_out;
    float* ws  = (float*)d_ws;

    float* henc   = ws;
    float* psi2   = ws + 32768;
    float* dcarry = ws + 36864;
    u16*   psi16  = (u16*)(ws + 69632);
    u16*   gbuf   = (u16*)(ws + 6248192);
    const size_t used = (size_t)6248192 * 4;
    size_t avail = (ws_size > used + 4096) ? (ws_size - used - 4096) : 0;
    int ct = (int)(avail / ((size_t)BB * 768 * 2));
    if (ct > TT) ct = TT;
    if (ct < 1) ct = 1;

    for (int t0 = 0; t0 < TT; t0 += ct) {
        const int len = (TT - t0 < ct) ? (TT - t0) : ct;
        const int nt = (len + 127) / 128;
        gemm_x_kernel<<<BB * nt, 768, 0, stream>>>(inputs, eWih, psi16, 0, t0, len, ct, nt, gbuf);
        enc_scan_kernel<<<BB, 1024, 0, stream>>>(gbuf, t0, len, ct, eWhh, ebih, ebhh, henc);
    }
    latent_kernel<<<BB, 256, 0, stream>>>(henc, eps, to_mu, to_ls, W1, b1, W2, b2, psi2, out);
    psi3_kernel<<<(NPSI + 255) / 256, 256, 0, stream>>>(psi2, W3, b3, psi16);
    for (int t0 = 0; t0 < TT; t0 += ct) {
        const int len = (TT - t0 < ct) ? (TT - t0) : ct;
        const int nt = (len + 127) / 128;
        gemm_x_kernel<<<BB * nt, 768, 0, stream>>>(inputs, gWih, psi16, 1, t0, len, ct, nt, gbuf);
        dec_scan_kernel<<<BB, 1024, 0, stream>>>(gbuf, t0, len, ct, state, gWhh, gbias, psi16, dcarry, out);
    }
    post_kernel<<<BB * 8, 256, 0, stream>>>(inputs, psi16, out);
}

// Round 5
// 4176.098 us; speedup vs baseline: 1.3862x; 1.3862x over previous
//
#include <hip/hip_runtime.h>

#define BB 128
#define TT 1024
#define INP 54
#define HUM 64
#define NPSI 96540
#define OFF_BH 65536
#define OFF_WIH 65792
#define OFF_C 79616
#define OFF_D 96000
#define OUT_MU 8388608
#define OUT_LS 8390656
#define OUT_HL 8392704

typedef unsigned int u32;
typedef unsigned short u16;
typedef _Float16 h2 __attribute__((ext_vector_type(2)));

__device__ __forceinline__ u32 pk(float a, float b) {
    h2 v; v.x = (_Float16)a; v.y = (_Float16)b;
    return __builtin_bit_cast(u32, v);
}
__device__ __forceinline__ float f16tof(u16 v) {
    return (float)__builtin_bit_cast(_Float16, v);
}
__device__ __forceinline__ u16 ftof16(float v) {
    return __builtin_bit_cast(u16, (_Float16)v);
}
__device__ __forceinline__ float lo16f(u32 v) { return f16tof((u16)(v & 0xffffu)); }
__device__ __forceinline__ float hi16f(u32 v) { return f16tof((u16)(v >> 16)); }
__device__ __forceinline__ h2 bch2(u32 a) { return __builtin_bit_cast(h2, a); }
// packed f16 fma: 2 MACs/inst (v_pk_fma_f16 via contraction)
__device__ __forceinline__ h2 pfma(u32 a, u32 b, h2 c) {
    return bch2(a) * bch2(b) + c;
}
__device__ __forceinline__ float hsum2(h2 a, h2 b) {
    h2 s = a + b; return (float)s.x + (float)s.y;
}
__device__ __forceinline__ float fsig(float x) { return 1.f / (1.f + __expf(-x)); }
__device__ __forceinline__ float ftanh(float x) { float e = __expf(2.f * x); return 1.f - 2.f / (e + 1.f); }

// quad reduction on the VALU pipe (DPP): all 4 lanes end with the full sum
__device__ __forceinline__ float qred(float v) {
#if __has_builtin(__builtin_amdgcn_mov_dpp)
    int x = __builtin_bit_cast(int, v);
    v += __builtin_bit_cast(float, __builtin_amdgcn_mov_dpp(x, 0xB1, 0xF, 0xF, true)); // [1,0,3,2]
    x = __builtin_bit_cast(int, v);
    v += __builtin_bit_cast(float, __builtin_amdgcn_mov_dpp(x, 0x4E, 0xF, 0xF, true)); // [2,3,0,1]
    return v;
#else
    v += __shfl_xor(v, 1); v += __shfl_xor(v, 2);
    return v;
#endif
}

// ------------------------------------------------------- x-side projections --
__global__ __launch_bounds__(768, 3) void gemm_x_kernel(
    const float* __restrict__ inp, const float* __restrict__ W0,
    const u16* __restrict__ psi16, int mode, int t0, int len, int ct, int nt,
    u16* __restrict__ gout)
{
    const int tid = threadIdx.x;
    const int b = blockIdx.x / nt, tc = blockIdx.x % nt;
    const int gr = tid;
    float w[INP];
    if (mode == 0 || gr < 512) {
        const float* wsrc = W0 + (size_t)gr * INP;
#pragma unroll
        for (int c = 0; c < INP; ++c) w[c] = wsrc[c];
    } else {
        const u16* wsrc = psi16 + (size_t)b * NPSI + OFF_WIH + (size_t)(gr - 512) * INP;
#pragma unroll
        for (int c = 0; c < INP; ++c) w[c] = f16tof(wsrc[c]);
    }
    const int tb = tc * 128;
    const int te = (tb + 128 < len) ? tb + 128 : len;
    for (int tl = tb; tl < te; ++tl) {
        const float* xr = inp + ((size_t)b * TT + t0 + tl) * INP;
        float a = 0.f;
#pragma unroll
        for (int c = 0; c < INP; ++c) a = __builtin_fmaf(xr[c], w[c], a);
        gout[((size_t)b * ct + tl) * 768 + gr] = ftof16(a);
    }
}

// ---------------------------------------------------------------- encoder ---
// 512 threads: l = tid&3 (64-h segment), g = tid>>2, rows j0=2g, j1=2g+1.
// 192 weight u32 in VGPRs (launch_bounds(512,2) -> 256 VGPR budget).
__global__ __launch_bounds__(512, 2) void enc_scan_kernel(
    const u16* __restrict__ gi, int t0, int len, int ct,
    const float* __restrict__ Whh, const float* __restrict__ bih,
    const float* __restrict__ bhh, float* __restrict__ hcarry)
{
    __shared__ __align__(16) u32 hpp[2][144];
    const int tid = threadIdx.x, b = blockIdx.x;
    const int l = tid & 3, g = tid >> 2;
    const int j0 = 2 * g, j1 = 2 * g + 1;

    u32 wr0[32], wz0[32], wn0[32], wr1[32], wz1[32], wn1[32];
    {
        const float* pr0 = Whh + (size_t)j0 * 256 + 64 * l;
        const float* pz0 = Whh + (size_t)(256 + j0) * 256 + 64 * l;
        const float* pn0 = Whh + (size_t)(512 + j0) * 256 + 64 * l;
        const float* pr1 = Whh + (size_t)j1 * 256 + 64 * l;
        const float* pz1 = Whh + (size_t)(256 + j1) * 256 + 64 * l;
        const float* pn1 = Whh + (size_t)(512 + j1) * 256 + 64 * l;
#pragma unroll
        for (int c = 0; c < 32; ++c) {
            wr0[c] = pk(pr0[2 * c], pr0[2 * c + 1]);
            wz0[c] = pk(pz0[2 * c], pz0[2 * c + 1]);
            wn0[c] = pk(pn0[2 * c], pn0[2 * c + 1]);
            wr1[c] = pk(pr1[2 * c], pr1[2 * c + 1]);
            wz1[c] = pk(pz1[2 * c], pz1[2 * c + 1]);
            wn1[c] = pk(pn1[2 * c], pn1[2 * c + 1]);
        }
    }
    const float brb0 = bih[j0] + bhh[j0],            brb1 = bih[j1] + bhh[j1];
    const float bzb0 = bih[256 + j0] + bhh[256 + j0], bzb1 = bih[256 + j1] + bhh[256 + j1];
    const float bib0 = bih[512 + j0],                 bib1 = bih[512 + j1];
    const float bhb0 = bhh[512 + j0],                 bhb1 = bhh[512 + j1];
    float hc0 = 0.f, hc1 = 0.f;
    if (t0 > 0) { hc0 = hcarry[(size_t)b * 256 + j0]; hc1 = hcarry[(size_t)b * 256 + j1]; }
    if (tid < 128) {
        u32 hv = 0u;
        if (t0 > 0) hv = pk(hcarry[(size_t)b * 256 + 2 * tid], hcarry[(size_t)b * 256 + 2 * tid + 1]);
        hpp[0][36 * (tid >> 5) + (tid & 31)] = hv;
    }
    __syncthreads();

    const u16* gbase = gi + (size_t)b * ct * 768;
    u32 c0 = *(const u32*)(gbase + 2 * g);
    u32 c1 = *(const u32*)(gbase + 256 + 2 * g);
    u32 c2 = *(const u32*)(gbase + 512 + 2 * g);
    const h2 z2 = {(_Float16)0.f, (_Float16)0.f};

    for (int tl = 0; tl < len; ++tl) {
        const int p = tl & 1;
        u32 n0 = 0, n1 = 0, n2 = 0;
        if (tl + 1 < len) {
            const u16* gn = gbase + (size_t)(tl + 1) * 768;
            n0 = *(const u32*)(gn + 2 * g);
            n1 = *(const u32*)(gn + 256 + 2 * g);
            n2 = *(const u32*)(gn + 512 + 2 * g);
        }
        h2 vr0[2], vz0[2], vn0[2], vr1[2], vz1[2], vn1[2];
#pragma unroll
        for (int i = 0; i < 2; ++i) {
            vr0[i] = z2; vz0[i] = z2; vn0[i] = z2;
            vr1[i] = z2; vz1[i] = z2; vn1[i] = z2;
        }
        const uint4* hq = (const uint4*)hpp[p];
#pragma unroll
        for (int cc = 0; cc < 8; ++cc) {
            uint4 q = hq[9 * l + cc];
            u32 qa[4] = {q.x, q.y, q.z, q.w};
            const int ai = cc & 1;
#pragma unroll
            for (int u = 0; u < 4; ++u) {
                const int c = cc * 4 + u;
                vr0[ai] = pfma(wr0[c], qa[u], vr0[ai]);
                vz0[ai] = pfma(wz0[c], qa[u], vz0[ai]);
                vn0[ai] = pfma(wn0[c], qa[u], vn0[ai]);
                vr1[ai] = pfma(wr1[c], qa[u], vr1[ai]);
                vz1[ai] = pfma(wz1[c], qa[u], vz1[ai]);
                vn1[ai] = pfma(wn1[c], qa[u], vn1[ai]);
            }
        }
        float ar0 = qred(hsum2(vr0[0], vr0[1]));
        float az0 = qred(hsum2(vz0[0], vz0[1]));
        float ah0 = qred(hsum2(vn0[0], vn0[1]));
        float ar1 = qred(hsum2(vr1[0], vr1[1]));
        float az1 = qred(hsum2(vz1[0], vz1[1]));
        float ah1 = qred(hsum2(vn1[0], vn1[1]));
        {
            float r0 = fsig(ar0 + lo16f(c0) + brb0);
            float z0 = fsig(az0 + lo16f(c1) + bzb0);
            float nn0 = ftanh(lo16f(c2) + bib0 + r0 * (ah0 + bhb0));
            float hn0 = (1.f - z0) * nn0 + z0 * hc0;
            float r1 = fsig(ar1 + hi16f(c0) + brb1);
            float z1 = fsig(az1 + hi16f(c1) + bzb1);
            float nn1 = ftanh(hi16f(c2) + bib1 + r1 * (ah1 + bhb1));
            float hn1 = (1.f - z1) * nn1 + z1 * hc1;
            hc0 = hn0; hc1 = hn1;
            if (l == 0) hpp[p ^ 1][36 * (g >> 5) + (g & 31)] = pk(hn0, hn1);
        }
        c0 = n0; c1 = n1; c2 = n2;
        __syncthreads();
    }
    if (l == 0) {
        hcarry[(size_t)b * 256 + j0] = hc0;
        hcarry[(size_t)b * 256 + j1] = hc1;
    }
}

// ----------------------------------------------------------------- latent ---
__global__ __launch_bounds__(256) void latent_kernel(
    const float* __restrict__ henc, const float* __restrict__ eps,
    const float* __restrict__ to_mu, const float* __restrict__ to_ls,
    const float* __restrict__ W1, const float* __restrict__ b1,
    const float* __restrict__ W2, const float* __restrict__ b2,
    float* __restrict__ psi2, float* __restrict__ out)
{
    __shared__ float h[256], zz[16], p1[256];
    const int tid = threadIdx.x, b = blockIdx.x;
    h[tid] = henc[(size_t)b * 256 + tid];
    __syncthreads();
    if (tid < 16) {
        float m = 0, s = 0;
        for (int k = 0; k < 256; ++k) {
            m += h[k] * to_mu[tid * 256 + k];
            s += h[k] * to_ls[tid * 256 + k];
        }
        out[OUT_MU + b * 16 + tid] = m;
        out[OUT_LS + b * 16 + tid] = s;
        zz[tid] = m + eps[b * 16 + tid] * __expf(s);
    }
    __syncthreads();
    {
        float a = b1[tid];
        for (int k = 0; k < 16; ++k) a += zz[k] * W1[tid * 16 + k];
        p1[tid] = ftanh(a);
    }
    __syncthreads();
    if (tid < 32) {
        float a = b2[tid];
        for (int k = 0; k < 256; ++k) a += p1[k] * W2[tid * 256 + k];
        psi2[b * 32 + tid] = a;
    }
}

// ------------------------------------------------------------------- psi3 ---
__global__ __launch_bounds__(256) void psi3_kernel(
    const float* __restrict__ psi2, const float* __restrict__ W3,
    const float* __restrict__ b3, u16* __restrict__ psi16)
{
    __shared__ float sp2[128 * 32];
    __shared__ float w3t[256 * 33];
    const int tid = threadIdx.x;
    const int n0 = blockIdx.x * 256;
    for (int idx = tid; idx < 4096; idx += 256) sp2[idx] = psi2[idx];
    for (int idx = tid; idx < 8192; idx += 256) {
        int row = idx >> 5, k = idx & 31;
        int n = n0 + row;
        w3t[row * 33 + k] = (n < NPSI) ? W3[(size_t)n * 32 + k] : 0.f;
    }
    __syncthreads();
    const int n = n0 + tid;
    if (n < NPSI) {
        float w[32];
#pragma unroll
        for (int k = 0; k < 32; ++k) w[k] = w3t[tid * 33 + k];
        const float bv = b3[n];
        for (int bi = 0; bi < 128; ++bi) {
            float a = bv;
#pragma unroll
            for (int k = 0; k < 32; ++k) a += sp2[bi * 32 + k] * w[k];
            psi16[(size_t)bi * NPSI + n] = ftof16(a);
        }
    }
}

// ------------------------------- decoder scan + pipelined fused C_p einsum --
// 512 threads. Matvec rows j0,j1 per thread; yhat: o=tid&63, s=tid>>6 (16 pairs).
__global__ __launch_bounds__(512, 2) void dec_scan_kernel(
    const u16* __restrict__ gx, int t0, int len, int ct,
    const float* __restrict__ state, const float* __restrict__ gWhh,
    const float* __restrict__ gbias, const u16* __restrict__ psi16,
    float* __restrict__ dcarry, float* __restrict__ out)
{
    __shared__ __align__(16) u32 hpp[2][144];
    __shared__ u32 cp[64 * 129];      // [o][pair q], stride 129 -> b32 2-way free
    __shared__ float part[2][8 * 64];
    const int tid = threadIdx.x, b = blockIdx.x;
    const int l = tid & 3, g = tid >> 2;
    const int j0 = 2 * g, j1 = 2 * g + 1;
    const u16* pc = psi16 + (size_t)b * NPSI;

    u32 wz0[32], wr0[32], wp0[32], wz1[32], wr1[32], wp1[32];
#pragma unroll
    for (int c = 0; c < 32; ++c) {
        const int h0 = 64 * l + 2 * c;
        wz0[c] = pk(gWhh[(size_t)h0 * 512 + j0], gWhh[(size_t)(h0 + 1) * 512 + j0]);
        wr0[c] = pk(gWhh[(size_t)h0 * 512 + 256 + j0], gWhh[(size_t)(h0 + 1) * 512 + 256 + j0]);
        wp0[c] = (u32)pc[(size_t)h0 * 256 + j0] | ((u32)pc[(size_t)(h0 + 1) * 256 + j0] << 16);
        wz1[c] = pk(gWhh[(size_t)h0 * 512 + j1], gWhh[(size_t)(h0 + 1) * 512 + j1]);
        wr1[c] = pk(gWhh[(size_t)h0 * 512 + 256 + j1], gWhh[(size_t)(h0 + 1) * 512 + 256 + j1]);
        wp1[c] = (u32)pc[(size_t)h0 * 256 + j1] | ((u32)pc[(size_t)(h0 + 1) * 256 + j1] << 16);
    }
    const float gzb0 = gbias[j0], gzb1 = gbias[j1];
    const float grb0 = gbias[256 + j0], grb1 = gbias[256 + j1];
    const float bhb0 = f16tof(pc[OFF_BH + j0]), bhb1 = f16tof(pc[OFF_BH + j1]);
    for (int idx = tid; idx < 8192; idx += 512) {
        const int q = idx >> 6, o = idx & 63;
        cp[o * 129 + q] = (u32)pc[OFF_C + (size_t)(2 * q) * 64 + o]
                        | ((u32)pc[OFF_C + (size_t)(2 * q + 1) * 64 + o] << 16);
    }
    const float* hsrc = (t0 == 0) ? state : dcarry;
    float hc0 = hsrc[(size_t)b * 256 + j0];
    float hc1 = hsrc[(size_t)b * 256 + j1];
    if (tid < 128) hpp[0][36 * (tid >> 5) + (tid & 31)] =
        pk(hsrc[(size_t)b * 256 + 2 * tid], hsrc[(size_t)b * 256 + 2 * tid + 1]);
    __syncthreads();

    const u16* gbase = gx + (size_t)b * ct * 768;
    const int o = tid & 63, s = tid >> 6;          // s == wave id (uniform)
    const int hqi = 36 * (s >> 1) + 16 * (s & 1);  // u32 idx of pair 16s
    u32 c0 = *(const u32*)(gbase + 2 * g);
    u32 c1 = *(const u32*)(gbase + 256 + 2 * g);
    u32 c2 = *(const u32*)(gbase + 512 + 2 * g);
    const h2 z2 = {(_Float16)0.f, (_Float16)0.f};

    for (int tl = 0; tl < len; ++tl) {
        const int p = tl & 1;
        u32 n0 = 0, n1 = 0, n2 = 0;
        if (tl + 1 < len) {
            const u16* gn = gbase + (size_t)(tl + 1) * 768;
            n0 = *(const u32*)(gn + 2 * g);
            n1 = *(const u32*)(gn + 256 + 2 * g);
            n2 = *(const u32*)(gn + 512 + 2 * g);
        }
        // yhat partials for h_{t0+tl-1} from hpp[p] (wave-uniform broadcast)
        {
            const uint4* h2q = (const uint4*)&hpp[p][hqi];
            uint4 qa = h2q[0], qb = h2q[1], qc = h2q[2], qd = h2q[3];
            u32 hv[16] = {qa.x, qa.y, qa.z, qa.w, qb.x, qb.y, qb.z, qb.w,
                          qc.x, qc.y, qc.z, qc.w, qd.x, qd.y, qd.z, qd.w};
            const int cbase = o * 129 + s * 16;
            h2 p0 = z2, p1 = z2;
#pragma unroll
            for (int i = 0; i < 8; ++i) {
                p0 = pfma(hv[2 * i], cp[cbase + 2 * i], p0);
                p1 = pfma(hv[2 * i + 1], cp[cbase + 2 * i + 1], p1);
            }
            part[p][s * 64 + o] = hsum2(p0, p1);
        }
        // recurrent matvec
        h2 vz0[2], vr0[2], vp0[2], vz1[2], vr1[2], vp1[2];
#pragma unroll
        for (int i = 0; i < 2; ++i) {
            vz0[i] = z2; vr0[i] = z2; vp0[i] = z2;
            vz1[i] = z2; vr1[i] = z2; vp1[i] = z2;
        }
        const uint4* hq = (const uint4*)hpp[p];
#pragma unroll
        for (int cc = 0; cc < 8; ++cc) {
            uint4 q = hq[9 * l + cc];
            u32 qa[4] = {q.x, q.y, q.z, q.w};
            const int ai = cc & 1;
#pragma unroll
            for (int u = 0; u < 4; ++u) {
                const int c = cc * 4 + u;
                vz0[ai] = pfma(wz0[c], qa[u], vz0[ai]);
                vr0[ai] = pfma(wr0[c], qa[u], vr0[ai]);
                vp0[ai] = pfma(wp0[c], qa[u], vp0[ai]);
                vz1[ai] = pfma(wz1[c], qa[u], vz1[ai]);
                vr1[ai] = pfma(wr1[c], qa[u], vr1[ai]);
                vp1[ai] = pfma(wp1[c], qa[u], vp1[ai]);
            }
        }
        float az0 = qred(hsum2(vz0[0], vz0[1]));
        float ar0 = qred(hsum2(vr0[0], vr0[1]));
        float ap0 = qred(hsum2(vp0[0], vp0[1]));
        float az1 = qred(hsum2(vz1[0], vz1[1]));
        float ar1 = qred(hsum2(vr1[0], vr1[1]));
        float ap1 = qred(hsum2(vp1[0], vp1[1]));
        {
            float zt0 = fsig(az0 + lo16f(c0) + gzb0);
            float rt0 = fsig(ar0 + lo16f(c1) + grb0);
            float eta0 = ftanh(lo16f(c2) + rt0 * ftanh(ap0 + bhb0));
            float hn0 = zt0 * hc0 + (1.f - zt0) * eta0;
            float zt1 = fsig(az1 + hi16f(c0) + gzb1);
            float rt1 = fsig(ar1 + hi16f(c1) + grb1);
            float eta1 = ftanh(hi16f(c2) + rt1 * ftanh(ap1 + bhb1));
            float hn1 = zt1 * hc1 + (1.f - zt1) * eta1;
            hc0 = hn0; hc1 = hn1;
            if (l == 0) hpp[p ^ 1][36 * (g >> 5) + (g & 31)] = pk(hn0, hn1);
        }
        // reduce partials of h_{t0+tl-2} -> y_{t0+tl-2}
        if (tid < 64 && tl >= 2) {
            float y = 0.f;
#pragma unroll
            for (int s2 = 0; s2 < 8; ++s2) y += part[p ^ 1][s2 * 64 + tid];
            out[((size_t)b * TT + t0 + tl - 2) * HUM + tid] = y;
        }
        c0 = n0; c1 = n1; c2 = n2;
        __syncthreads();
    }
    // tail: y_{t0+len-2} then partials+reduce for y_{t0+len-1}
    {
        const int pf = (len - 1) & 1;
        if (tid < 64 && len >= 2) {
            float y = 0.f;
#pragma unroll
            for (int s2 = 0; s2 < 8; ++s2) y += part[pf][s2 * 64 + tid];
            out[((size_t)b * TT + t0 + len - 2) * HUM + tid] = y;
        }
        const int pl = len & 1;
        {
            const uint4* h2q = (const uint4*)&hpp[pl][hqi];
            uint4 qa = h2q[0], qb = h2q[1], qc = h2q[2], qd = h2q[3];
            u32 hv[16] = {qa.x, qa.y, qa.z, qa.w, qb.x, qb.y, qb.z, qb.w,
                          qc.x, qc.y, qc.z, qc.w, qd.x, qd.y, qd.z, qd.w};
            const int cbase = o * 129 + s * 16;
            h2 p0 = z2, p1 = z2;
#pragma unroll
            for (int i = 0; i < 8; ++i) {
                p0 = pfma(hv[2 * i], cp[cbase + 2 * i], p0);
                p1 = pfma(hv[2 * i + 1], cp[cbase + 2 * i + 1], p1);
            }
            part[pl][s * 64 + o] = hsum2(p0, p1);
        }
        __syncthreads();
        if (tid < 64) {
            float y = 0.f;
#pragma unroll
            for (int s2 = 0; s2 < 8; ++s2) y += part[pl][s2 * 64 + tid];
            out[((size_t)b * TT + t0 + len - 1) * HUM + tid] = y;
        }
    }
    if (l == 0) {
        dcarry[(size_t)b * 256 + j0] = hc0;
        dcarry[(size_t)b * 256 + j1] = hc1;
        if (t0 + len == TT) {
            out[OUT_HL + (size_t)b * 256 + j0] = hc0;
            out[OUT_HL + (size_t)b * 256 + j1] = hc1;
        }
    }
}

// ------------------------------------------------- x add + D_p einsum fixup --
__global__ __launch_bounds__(256) void post_kernel(
    const float* __restrict__ inp, const u16* __restrict__ psi16,
    float* __restrict__ out)
{
    __shared__ float xs[128][55];
    __shared__ float ds[INP][10];
    const int tid = threadIdx.x;
    const int b = blockIdx.x >> 3, tile = blockIdx.x & 7;
    const int t0 = tile * 128;
    const u16* pc = psi16 + (size_t)b * NPSI;
    for (int idx = tid; idx < 540; idx += 256)
        ds[idx / 10][idx % 10] = f16tof(pc[OFF_D + idx]);
    for (int idx = tid; idx < 128 * INP; idx += 256) {
        const int t = idx / INP, d = idx % INP;
        xs[t][d] = inp[((size_t)b * TT + t0 + t) * INP + d];
    }
    __syncthreads();
    for (int i = 0; i < 32; ++i) {
        const int flat = i * 256 + tid;
        const int t = flat >> 6, o = flat & 63;
        const size_t oi = ((size_t)b * TT + t0 + t) * HUM + o;
        float y = out[oi];
        if (o < INP) y += xs[t][o];
        else {
            float acc = 0.f;
            for (int d = 0; d < INP; ++d) acc += xs[t][d] * ds[d][o - INP];
            y += acc;
        }
        out[oi] = y;
    }
}

// ----------------------------------------------------------------- launch ---
extern "C" void kernel_launch(void* const* d_in, const int* in_sizes, int n_in,
                              void* d_out, int out_size, void* d_ws, size_t ws_size,
                              hipStream_t stream)
{
    const float* inputs = (const float*)d_in[0];
    const float* state  = (const float*)d_in[1];
    const float* eps    = (const float*)d_in[2];
    const float* eWih   = (const float*)d_in[3];
    const float* eWhh   = (const float*)d_in[4];
    const float* ebih   = (const float*)d_in[5];
    const float* ebhh   = (const float*)d_in[6];
    const float* to_mu  = (const float*)d_in[7];
    const float* to_ls  = (const float*)d_in[8];
    const float* W1     = (const float*)d_in[9];
    const float* b1     = (const float*)d_in[10];
    const float* W2     = (const float*)d_in[11];
    const float* b2     = (const float*)d_in[12];
    const float* W3     = (const float*)d_in[13];
    const float* b3     = (const float*)d_in[14];
    const float* gWih   = (const float*)d_in[15];
    const float* gWhh   = (const float*)d_in[16];
    const float* gbias  = (const float*)d_in[17];
    float* out = (float*)d_out;
    float* ws  = (float*)d_ws;

    float* henc   = ws;
    float* psi2   = ws + 32768;
    float* dcarry = ws + 36864;
    u16*   psi16  = (u16*)(ws + 69632);
    u16*   gbuf   = (u16*)(ws + 6248192);
    const size_t used = (size_t)6248192 * 4;
    size_t avail = (ws_size > used + 4096) ? (ws_size - used - 4096) : 0;
    int ct = (int)(avail / ((size_t)BB * 768 * 2));
    if (ct > TT) ct = TT;
    if (ct < 1) ct = 1;

    for (int t0 = 0; t0 < TT; t0 += ct) {
        const int len = (TT - t0 < ct) ? (TT - t0) : ct;
        const int nt = (len + 127) / 128;
        gemm_x_kernel<<<BB * nt, 768, 0, stream>>>(inputs, eWih, psi16, 0, t0, len, ct, nt, gbuf);
        enc_scan_kernel<<<BB, 512, 0, stream>>>(gbuf, t0, len, ct, eWhh, ebih, ebhh, henc);
    }
    latent_kernel<<<BB, 256, 0, stream>>>(henc, eps, to_mu, to_ls, W1, b1, W2, b2, psi2, out);
    psi3_kernel<<<(NPSI + 255) / 256, 256, 0, stream>>>(psi2, W3, b3, psi16);
    for (int t0 = 0; t0 < TT; t0 += ct) {
        const int len = (TT - t0 < ct) ? (TT - t0) : ct;
        const int nt = (len + 127) / 128;
        gemm_x_kernel<<<BB * nt, 768, 0, stream>>>(inputs, gWih, psi16, 1, t0, len, ct, nt, gbuf);
        dec_scan_kernel<<<BB, 512, 0, stream>>>(gbuf, t0, len, ct, state, gWhh, gbias, psi16, dcarry, out);
    }
    post_kernel<<<BB * 8, 256, 0, stream>>>(inputs, psi16, out);
}

// Round 6
// 3910.540 us; speedup vs baseline: 1.4803x; 1.0679x over previous
//
#include <hip/hip_runtime.h>

#define BB 128
#define TT 1024
#define INP 54
#define HUM 64
#define NPSI 96540
#define OFF_BH 65536
#define OFF_WIH 65792
#define OFF_C 79616
#define OFF_D 96000
#define OUT_MU 8388608
#define OUT_LS 8390656
#define OUT_HL 8392704

typedef unsigned int u32;
typedef unsigned short u16;
typedef _Float16 h2 __attribute__((ext_vector_type(2)));
typedef _Float16 f16x8 __attribute__((ext_vector_type(8)));
typedef float f32x4 __attribute__((ext_vector_type(4)));

__device__ __forceinline__ u32 pk(float a, float b) {
    h2 v; v.x = (_Float16)a; v.y = (_Float16)b;
    return __builtin_bit_cast(u32, v);
}
__device__ __forceinline__ float f16tof(u16 v) {
    return (float)__builtin_bit_cast(_Float16, v);
}
__device__ __forceinline__ u16 ftof16(float v) {
    return __builtin_bit_cast(u16, (_Float16)v);
}
__device__ __forceinline__ h2 bch2(u32 a) { return __builtin_bit_cast(h2, a); }
__device__ __forceinline__ h2 pfma(u32 a, u32 b, h2 c) {
    return bch2(a) * bch2(b) + c;
}
__device__ __forceinline__ float hsum2(h2 a, h2 b) {
    h2 s = a + b; return (float)s.x + (float)s.y;
}
__device__ __forceinline__ float fsig(float x) { return 1.f / (1.f + __expf(-x)); }
__device__ __forceinline__ float ftanh(float x) { float e = __expf(2.f * x); return 1.f - 2.f / (e + 1.f); }

// ------------------------------------------------------- x-side projections --
__global__ __launch_bounds__(768, 3) void gemm_x_kernel(
    const float* __restrict__ inp, const float* __restrict__ W0,
    const u16* __restrict__ psi16, int mode, int t0, int len, int ct, int nt,
    u16* __restrict__ gout)
{
    const int tid = threadIdx.x;
    const int b = blockIdx.x / nt, tc = blockIdx.x % nt;
    const int gr = tid;
    float w[INP];
    if (mode == 0 || gr < 512) {
        const float* wsrc = W0 + (size_t)gr * INP;
#pragma unroll
        for (int c = 0; c < INP; ++c) w[c] = wsrc[c];
    } else {
        const u16* wsrc = psi16 + (size_t)b * NPSI + OFF_WIH + (size_t)(gr - 512) * INP;
#pragma unroll
        for (int c = 0; c < INP; ++c) w[c] = f16tof(wsrc[c]);
    }
    const int tb = tc * 128;
    const int te = (tb + 128 < len) ? tb + 128 : len;
    for (int tl = tb; tl < te; ++tl) {
        const float* xr = inp + ((size_t)b * TT + t0 + tl) * INP;
        float a = 0.f;
#pragma unroll
        for (int c = 0; c < INP; ++c) a = __builtin_fmaf(xr[c], w[c], a);
        gout[((size_t)b * ct + tl) * 768 + gr] = ftof16(a);
    }
}

// ---------------------------------------------------------------- encoder ---
// 512 thr = 8 waves. Wave wv owns rows [96wv, 96wv+96) as 6 MFMA row-tiles.
// A (weights) resident in 192 regs/thread; B = h broadcast across cols.
__global__ __launch_bounds__(512, 2) void enc_scan_kernel(
    const u16* __restrict__ gi, int t0, int len, int ct,
    const float* __restrict__ Whh, const float* __restrict__ bih,
    const float* __restrict__ bhh, float* __restrict__ hcarry)
{
    __shared__ __align__(16) u32 hpx[2][128];
    __shared__ __align__(16) float grow[768];
    const int tid = threadIdx.x, b = blockIdx.x;
    const int lane = tid & 63, wv = tid >> 6;
    const int rlo = lane & 15, kb = lane >> 4;

    // A fragments: wf[t][kt] = W rows [96wv+16t+rlo], k in [32kt+8kb, +8)
    f16x8 wf[6][8];
#pragma unroll
    for (int t = 0; t < 6; ++t) {
        const float* src = Whh + (size_t)(96 * wv + 16 * t + rlo) * 256 + 8 * kb;
#pragma unroll
        for (int kt = 0; kt < 8; ++kt)
#pragma unroll
            for (int e = 0; e < 8; ++e)
                wf[t][kt][e] = (_Float16)src[32 * kt + e];
    }
    float brb = 0, bzb = 0, bib = 0, bhb = 0, hc = 0;
    if (tid < 256) {
        brb = bih[tid] + bhh[tid];
        bzb = bih[256 + tid] + bhh[256 + tid];
        bib = bih[512 + tid];
        bhb = bhh[512 + tid];
        if (t0 > 0) hc = hcarry[(size_t)b * 256 + tid];
    }
    if (tid < 128) {
        u32 hv = 0u;
        if (t0 > 0) hv = pk(hcarry[(size_t)b * 256 + 2 * tid], hcarry[(size_t)b * 256 + 2 * tid + 1]);
        hpx[0][tid] = hv;
    }
    __syncthreads();

    const u16* gbase = gi + (size_t)b * ct * 768;
    u16 cr = 0, cz = 0, cn = 0;
    if (tid < 256) { cr = gbase[tid]; cz = gbase[256 + tid]; cn = gbase[512 + tid]; }

    for (int tl = 0; tl < len; ++tl) {
        const int p = tl & 1;
        u16 nr = 0, nz = 0, nn2 = 0;
        if (tid < 256 && tl + 1 < len) {
            const u16* gn = gbase + (size_t)(tl + 1) * 768;
            nr = gn[tid]; nz = gn[256 + tid]; nn2 = gn[512 + tid];
        }
        f32x4 acc[6];
#pragma unroll
        for (int t = 0; t < 6; ++t) acc[t] = (f32x4){0.f, 0.f, 0.f, 0.f};
#pragma unroll
        for (int kt = 0; kt < 8; ++kt) {
            f16x8 bf = *(const f16x8*)&hpx[p][16 * kt + 4 * kb];
#pragma unroll
            for (int t = 0; t < 6; ++t)
                acc[t] = __builtin_amdgcn_mfma_f32_16x16x32_f16(wf[t][kt], bf, acc[t], 0, 0, 0);
        }
        if (rlo == 0) {
#pragma unroll
            for (int t = 0; t < 6; ++t)
                *(f32x4*)&grow[96 * wv + 16 * t + 4 * kb] = acc[t];
        }
        __syncthreads();   // grow ready
        if (tid < 256) {
            float r = fsig(grow[tid] + f16tof(cr) + brb);
            float z = fsig(grow[256 + tid] + f16tof(cz) + bzb);
            float nn = ftanh(f16tof(cn) + bib + r * (grow[512 + tid] + bhb));
            float hn = (1.f - z) * nn + z * hc;
            hc = hn;
            float ho = __shfl_xor(hn, 1);
            if (!(tid & 1)) hpx[p ^ 1][tid >> 1] = pk(hn, ho);
        }
        cr = nr; cz = nz; cn = nn2;
        __syncthreads();   // h published
    }
    if (tid < 256) hcarry[(size_t)b * 256 + tid] = hc;
}

// ----------------------------------------------------------------- latent ---
__global__ __launch_bounds__(256) void latent_kernel(
    const float* __restrict__ henc, const float* __restrict__ eps,
    const float* __restrict__ to_mu, const float* __restrict__ to_ls,
    const float* __restrict__ W1, const float* __restrict__ b1,
    const float* __restrict__ W2, const float* __restrict__ b2,
    float* __restrict__ psi2, float* __restrict__ out)
{
    __shared__ float h[256], zz[16], p1[256];
    const int tid = threadIdx.x, b = blockIdx.x;
    h[tid] = henc[(size_t)b * 256 + tid];
    __syncthreads();
    if (tid < 16) {
        float m = 0, s = 0;
        for (int k = 0; k < 256; ++k) {
            m += h[k] * to_mu[tid * 256 + k];
            s += h[k] * to_ls[tid * 256 + k];
        }
        out[OUT_MU + b * 16 + tid] = m;
        out[OUT_LS + b * 16 + tid] = s;
        zz[tid] = m + eps[b * 16 + tid] * __expf(s);
    }
    __syncthreads();
    {
        float a = b1[tid];
        for (int k = 0; k < 16; ++k) a += zz[k] * W1[tid * 16 + k];
        p1[tid] = ftanh(a);
    }
    __syncthreads();
    if (tid < 32) {
        float a = b2[tid];
        for (int k = 0; k < 256; ++k) a += p1[k] * W2[tid * 256 + k];
        psi2[b * 32 + tid] = a;
    }
}

// ------------------------------------------------------------------- psi3 ---
__global__ __launch_bounds__(256) void psi3_kernel(
    const float* __restrict__ psi2, const float* __restrict__ W3,
    const float* __restrict__ b3, u16* __restrict__ psi16)
{
    __shared__ float sp2[128 * 32];
    __shared__ float w3t[256 * 33];
    const int tid = threadIdx.x;
    const int n0 = blockIdx.x * 256;
    for (int idx = tid; idx < 4096; idx += 256) sp2[idx] = psi2[idx];
    for (int idx = tid; idx < 8192; idx += 256) {
        int row = idx >> 5, k = idx & 31;
        int n = n0 + row;
        w3t[row * 33 + k] = (n < NPSI) ? W3[(size_t)n * 32 + k] : 0.f;
    }
    __syncthreads();
    const int n = n0 + tid;
    if (n < NPSI) {
        float w[32];
#pragma unroll
        for (int k = 0; k < 32; ++k) w[k] = w3t[tid * 33 + k];
        const float bv = b3[n];
        for (int bi = 0; bi < 128; ++bi) {
            float a = bv;
#pragma unroll
            for (int k = 0; k < 32; ++k) a += sp2[bi * 32 + k] * w[k];
            psi16[(size_t)bi * NPSI + n] = ftof16(a);
        }
    }
}

// ------------------------------- decoder scan (MFMA) + fused C_p einsum -----
// Row order: 0-255 z, 256-511 r (both from gWhh cols), 512-767 p (Whh_p).
__global__ __launch_bounds__(512, 2) void dec_scan_kernel(
    const u16* __restrict__ gx, int t0, int len, int ct,
    const float* __restrict__ state, const float* __restrict__ gWhh,
    const float* __restrict__ gbias, const u16* __restrict__ psi16,
    float* __restrict__ dcarry, float* __restrict__ out)
{
    __shared__ __align__(16) u32 hpx[2][128];
    __shared__ __align__(16) float grow[768];
    __shared__ u32 cp[64 * 129];       // [o][pair q], stride 129 -> 2-way free
    __shared__ float part[2][8 * 64];
    const int tid = threadIdx.x, b = blockIdx.x;
    const int lane = tid & 63, wv = tid >> 6;
    const int rlo = lane & 15, kb = lane >> 4;
    const u16* pc = psi16 + (size_t)b * NPSI;

    f16x8 wf[6][8];
#pragma unroll
    for (int t = 0; t < 6; ++t) {
        const int R = 96 * wv + 16 * t + rlo;
        if (R < 512) {   // uniform per tile
            const float* src = gWhh + R;
#pragma unroll
            for (int kt = 0; kt < 8; ++kt)
#pragma unroll
                for (int e = 0; e < 8; ++e)
                    wf[t][kt][e] = (_Float16)src[(size_t)(32 * kt + 8 * kb + e) * 512];
        } else {
            const u16* src = pc + (R - 512);
#pragma unroll
            for (int kt = 0; kt < 8; ++kt)
#pragma unroll
                for (int e = 0; e < 8; ++e)
                    wf[t][kt][e] = __builtin_bit_cast(_Float16, src[(size_t)(32 * kt + 8 * kb + e) * 256]);
        }
    }
    float gzb = 0, grb = 0, bhb = 0, hc = 0;
    if (tid < 256) {
        gzb = gbias[tid];
        grb = gbias[256 + tid];
        bhb = f16tof(pc[OFF_BH + tid]);
    }
    for (int idx = tid; idx < 8192; idx += 512) {
        const int q = idx >> 6, o = idx & 63;
        cp[o * 129 + q] = (u32)pc[OFF_C + (size_t)(2 * q) * 64 + o]
                        | ((u32)pc[OFF_C + (size_t)(2 * q + 1) * 64 + o] << 16);
    }
    const float* hsrc = (t0 == 0) ? state : dcarry;
    if (tid < 256) hc = hsrc[(size_t)b * 256 + tid];
    if (tid < 128) hpx[0][tid] =
        pk(hsrc[(size_t)b * 256 + 2 * tid], hsrc[(size_t)b * 256 + 2 * tid + 1]);
    __syncthreads();

    const u16* gbase = gx + (size_t)b * ct * 768;
    const h2 z2 = {(_Float16)0.f, (_Float16)0.f};
    u16 cz = 0, crr = 0, cnn = 0;
    if (tid < 256) { cz = gbase[tid]; crr = gbase[256 + tid]; cnn = gbase[512 + tid]; }

    for (int tl = 0; tl < len; ++tl) {
        const int p = tl & 1;
        u16 nz = 0, nr = 0, nn2 = 0;
        if (tid < 256 && tl + 1 < len) {
            const u16* gn = gbase + (size_t)(tl + 1) * 768;
            nz = gn[tid]; nr = gn[256 + tid]; nn2 = gn[512 + tid];
        }
        // yhat partials for h_{t-1} from hpx[p] (o=lane, s=wv)
        {
            const uint4* h2q = (const uint4*)&hpx[p][16 * wv];
            const int cbase = lane * 129 + wv * 16;
            h2 p0 = z2, p1 = z2;
            {
                uint4 qa = h2q[0], qb = h2q[1];
                p0 = pfma(qa.x, cp[cbase + 0], p0);
                p1 = pfma(qa.y, cp[cbase + 1], p1);
                p0 = pfma(qa.z, cp[cbase + 2], p0);
                p1 = pfma(qa.w, cp[cbase + 3], p1);
                p0 = pfma(qb.x, cp[cbase + 4], p0);
                p1 = pfma(qb.y, cp[cbase + 5], p1);
                p0 = pfma(qb.z, cp[cbase + 6], p0);
                p1 = pfma(qb.w, cp[cbase + 7], p1);
            }
            {
                uint4 qc = h2q[2], qd = h2q[3];
                p0 = pfma(qc.x, cp[cbase + 8], p0);
                p1 = pfma(qc.y, cp[cbase + 9], p1);
                p0 = pfma(qc.z, cp[cbase + 10], p0);
                p1 = pfma(qc.w, cp[cbase + 11], p1);
                p0 = pfma(qd.x, cp[cbase + 12], p0);
                p1 = pfma(qd.y, cp[cbase + 13], p1);
                p0 = pfma(qd.z, cp[cbase + 14], p0);
                p1 = pfma(qd.w, cp[cbase + 15], p1);
            }
            part[p][wv * 64 + lane] = hsum2(p0, p1);
        }
        // y_{t-2} reduce
        if (tid < 64 && tl >= 2) {
            float y = 0.f;
#pragma unroll
            for (int s2 = 0; s2 < 8; ++s2) y += part[p ^ 1][s2 * 64 + tid];
            out[((size_t)b * TT + t0 + tl - 2) * HUM + tid] = y;
        }
        // recurrent matvec on the matrix pipe
        f32x4 acc[6];
#pragma unroll
        for (int t = 0; t < 6; ++t) acc[t] = (f32x4){0.f, 0.f, 0.f, 0.f};
#pragma unroll
        for (int kt = 0; kt < 8; ++kt) {
            f16x8 bf = *(const f16x8*)&hpx[p][16 * kt + 4 * kb];
#pragma unroll
            for (int t = 0; t < 6; ++t)
                acc[t] = __builtin_amdgcn_mfma_f32_16x16x32_f16(wf[t][kt], bf, acc[t], 0, 0, 0);
        }
        if (rlo == 0) {
#pragma unroll
            for (int t = 0; t < 6; ++t)
                *(f32x4*)&grow[96 * wv + 16 * t + 4 * kb] = acc[t];
        }
        __syncthreads();   // grow ready
        if (tid < 256) {
            float zt = fsig(grow[tid] + f16tof(cz) + gzb);
            float rt = fsig(grow[256 + tid] + f16tof(crr) + grb);
            float eta = ftanh(f16tof(cnn) + rt * ftanh(grow[512 + tid] + bhb));
            float hn = zt * hc + (1.f - zt) * eta;
            hc = hn;
            float ho = __shfl_xor(hn, 1);
            if (!(tid & 1)) hpx[p ^ 1][tid >> 1] = pk(hn, ho);
        }
        cz = nz; crr = nr; cnn = nn2;
        __syncthreads();   // h published
    }
    // tail
    {
        const int pf = (len - 1) & 1;
        if (tid < 64 && len >= 2) {
            float y = 0.f;
#pragma unroll
            for (int s2 = 0; s2 < 8; ++s2) y += part[pf][s2 * 64 + tid];
            out[((size_t)b * TT + t0 + len - 2) * HUM + tid] = y;
        }
        const int pl = len & 1;
        {
            const uint4* h2q = (const uint4*)&hpx[pl][16 * wv];
            const int cbase = lane * 129 + wv * 16;
            h2 p0 = z2, p1 = z2;
            uint4 qa = h2q[0], qb = h2q[1], qc = h2q[2], qd = h2q[3];
            p0 = pfma(qa.x, cp[cbase + 0], p0);
            p1 = pfma(qa.y, cp[cbase + 1], p1);
            p0 = pfma(qa.z, cp[cbase + 2], p0);
            p1 = pfma(qa.w, cp[cbase + 3], p1);
            p0 = pfma(qb.x, cp[cbase + 4], p0);
            p1 = pfma(qb.y, cp[cbase + 5], p1);
            p0 = pfma(qb.z, cp[cbase + 6], p0);
            p1 = pfma(qb.w, cp[cbase + 7], p1);
            p0 = pfma(qc.x, cp[cbase + 8], p0);
            p1 = pfma(qc.y, cp[cbase + 9], p1);
            p0 = pfma(qc.z, cp[cbase + 10], p0);
            p1 = pfma(qc.w, cp[cbase + 11], p1);
            p0 = pfma(qd.x, cp[cbase + 12], p0);
            p1 = pfma(qd.y, cp[cbase + 13], p1);
            p0 = pfma(qd.z, cp[cbase + 14], p0);
            p1 = pfma(qd.w, cp[cbase + 15], p1);
            part[pl][wv * 64 + lane] = hsum2(p0, p1);
        }
        __syncthreads();
        if (tid < 64) {
            float y = 0.f;
#pragma unroll
            for (int s2 = 0; s2 < 8; ++s2) y += part[pl][s2 * 64 + tid];
            out[((size_t)b * TT + t0 + len - 1) * HUM + tid] = y;
        }
    }
    if (tid < 256) {
        dcarry[(size_t)b * 256 + tid] = hc;
        if (t0 + len == TT) out[OUT_HL + (size_t)b * 256 + tid] = hc;
    }
}

// ------------------------------------------------- x add + D_p einsum fixup --
__global__ __launch_bounds__(256) void post_kernel(
    const float* __restrict__ inp, const u16* __restrict__ psi16,
    float* __restrict__ out)
{
    __shared__ float xs[128][55];
    __shared__ float ds[INP][10];
    const int tid = threadIdx.x;
    const int b = blockIdx.x >> 3, tile = blockIdx.x & 7;
    const int t0 = tile * 128;
    const u16* pc = psi16 + (size_t)b * NPSI;
    for (int idx = tid; idx < 540; idx += 256)
        ds[idx / 10][idx % 10] = f16tof(pc[OFF_D + idx]);
    for (int idx = tid; idx < 128 * INP; idx += 256) {
        const int t = idx / INP, d = idx % INP;
        xs[t][d] = inp[((size_t)b * TT + t0 + t) * INP + d];
    }
    __syncthreads();
    for (int i = 0; i < 32; ++i) {
        const int flat = i * 256 + tid;
        const int t = flat >> 6, o = flat & 63;
        const size_t oi = ((size_t)b * TT + t0 + t) * HUM + o;
        float y = out[oi];
        if (o < INP) y += xs[t][o];
        else {
            float acc = 0.f;
            for (int d = 0; d < INP; ++d) acc += xs[t][d] * ds[d][o - INP];
            y += acc;
        }
        out[oi] = y;
    }
}

// ----------------------------------------------------------------- launch ---
extern "C" void kernel_launch(void* const* d_in, const int* in_sizes, int n_in,
                              void* d_out, int out_size, void* d_ws, size_t ws_size,
                              hipStream_t stream)
{
    const float* inputs = (const float*)d_in[0];
    const float* state  = (const float*)d_in[1];
    const float* eps    = (const float*)d_in[2];
    const float* eWih   = (const float*)d_in[3];
    const float* eWhh   = (const float*)d_in[4];
    const float* ebih   = (const float*)d_in[5];
    const float* ebhh   = (const float*)d_in[6];
    const float* to_mu  = (const float*)d_in[7];
    const float* to_ls  = (const float*)d_in[8];
    const float* W1     = (const float*)d_in[9];
    const float* b1     = (const float*)d_in[10];
    const float* W2     = (const float*)d_in[11];
    const float* b2     = (const float*)d_in[12];
    const float* W3     = (const float*)d_in[13];
    const float* b3     = (const float*)d_in[14];
    const float* gWih   = (const float*)d_in[15];
    const float* gWhh   = (const float*)d_in[16];
    const float* gbias  = (const float*)d_in[17];
    float* out = (float*)d_out;
    float* ws  = (float*)d_ws;

    float* henc   = ws;
    float* psi2   = ws + 32768;
    float* dcarry = ws + 36864;
    u16*   psi16  = (u16*)(ws + 69632);
    u16*   gbuf   = (u16*)(ws + 6248192);
    const size_t used = (size_t)6248192 * 4;
    size_t avail = (ws_size > used + 4096) ? (ws_size - used - 4096) : 0;
    int ct = (int)(avail / ((size_t)BB * 768 * 2));
    if (ct > TT) ct = TT;
    if (ct < 1) ct = 1;

    for (int t0 = 0; t0 < TT; t0 += ct) {
        const int len = (TT - t0 < ct) ? (TT - t0) : ct;
        const int nt = (len + 127) / 128;
        gemm_x_kernel<<<BB * nt, 768, 0, stream>>>(inputs, eWih, psi16, 0, t0, len, ct, nt, gbuf);
        enc_scan_kernel<<<BB, 512, 0, stream>>>(gbuf, t0, len, ct, eWhh, ebih, ebhh, henc);
    }
    latent_kernel<<<BB, 256, 0, stream>>>(henc, eps, to_mu, to_ls, W1, b1, W2, b2, psi2, out);
    psi3_kernel<<<(NPSI + 255) / 256, 256, 0, stream>>>(psi2, W3, b3, psi16);
    for (int t0 = 0; t0 < TT; t0 += ct) {
        const int len = (TT - t0 < ct) ? (TT - t0) : ct;
        const int nt = (len + 127) / 128;
        gemm_x_kernel<<<BB * nt, 768, 0, stream>>>(inputs, gWih, psi16, 1, t0, len, ct, nt, gbuf);
        dec_scan_kernel<<<BB, 512, 0, stream>>>(gbuf, t0, len, ct, state, gWhh, gbias, psi16, dcarry, out);
    }
    post_kernel<<<BB * 8, 256, 0, stream>>>(inputs, psi16, out);
}